// Round 4
// baseline (157.330 us; speedup 1.0000x reference)
//
#include <hip/hip_runtime.h>
#include <hip/hip_bf16.h>

// DifferentiableRenderer R4: scatter VALUES (float2 a,t) into the LDS grid,
// not u16 indices. R3 (41 us) was bound by march-time pre[] gathers
// fragmenting into ~40-64 L2 lines per wave (~1.3 GB L2 traffic ~= 38 us).
// Scatter-side pre[v] reads are fully coalesced (v = tid + it*1024), so
// moving the value fetch to scatter removes ALL data-dependent gathers.
//
// float2 40^3 grid = 512 KB -> z split into 4 slabs of depth 10
// ([10][1600] float2 = 125 KB dynamic LDS, 1 block/CU, 16 waves).
// Each thread caches its 32 destination cells (packed u16 pairs, 16 VGPR)
// and 32 float2 values (64 VGPR) once, replays per slab with a range test.
// Empty cell = (0,0): S += T*0*0, T *= 1-0 -- exact no-op, matching
// sigmoid(-1e9) == 0 in fp32.
//
// Numerics unchanged from R2/R3 (absmax 0.0): transform
// c = fmaf(z,R2c, fmaf(y,R1c, x*R0c)) + 20, clip [0,39], trunc;
// march S = fmaf(T*t, a, S), T *= (1-t); sigmoids = 1/(1+expf(-x)).

#define NBATCH 512
#define G      40
#define NRAYS  (G*G)       // 1600
#define NVOX   32768

// ---------- prep: per-voxel sigmoid table ----------
__global__ __launch_bounds__(256)
void prep_kernel(const float* __restrict__ ab, const float* __restrict__ at,
                 float2* __restrict__ pre)
{
    const int i = blockIdx.x * 256 + threadIdx.x;
    if (i < NVOX)
        pre[i] = make_float2(1.f / (1.f + expf(-ab[i])),
                             1.f / (1.f + expf(-at[i])));
}

// ---------- render: value grid in LDS, G/DEPTH z-slab passes ----------
template<int DEPTH, bool USE_PRE>
__global__ __launch_bounds__(1024)
void render_kernel(const float* __restrict__ Rall,
                   const float2* __restrict__ pre,
                   const float* __restrict__ ab,
                   const float* __restrict__ at,
                   float* __restrict__ out)
{
    constexpr int NP    = G / DEPTH;       // passes
    constexpr int CELLS = DEPTH * NRAYS;   // cells per slab
    extern __shared__ float2 grid[];       // [DEPTH][NRAYS], z-major

    const int b   = blockIdx.x;
    const int tid = threadIdx.x;

    const float* R = Rall + b * 9;
    const float r00 = R[0], r01 = R[1], r02 = R[2];
    const float r10 = R[3], r11 = R[4], r12 = R[5];
    const float r20 = R[6], r21 = R[7], r22 = R[8];

    // v = tid + it*1024  =>  i = it, j = (tid>>5)&31, k = tid&31
    const float y = (float)((tid >> 5) & 31) - 16.f;
    const float z = (float)(tid & 31) - 16.f;

    // --- cache: 32 destination cells (u16-packed) + 32 float2 values ---
    unsigned cpk[16];
    float2   val[32];
    #pragma unroll
    for (int it = 0; it < 32; ++it) {
        const float x = (float)it - 16.f;
        const float c0 = fmaf(z, r20, fmaf(y, r10, x * r00)) + 20.f;
        const float c1 = fmaf(z, r21, fmaf(y, r11, x * r01)) + 20.f;
        const float c2 = fmaf(z, r22, fmaf(y, r12, x * r02)) + 20.f;
        const int i0 = (int)fminf(fmaxf(c0, 0.f), 39.f);
        const int i1 = (int)fminf(fmaxf(c1, 0.f), 39.f);
        const int i2 = (int)fminf(fmaxf(c2, 0.f), 39.f);
        const unsigned cell = (unsigned)(i2 * NRAYS + i0 * G + i1); // < 64000, fits u16
        if (it & 1) cpk[it >> 1] |= cell << 16;
        else        cpk[it >> 1]  = cell;
        const int v = tid + (it << 10);
        if (USE_PRE) {
            val[it] = pre[v];                       // coalesced 8B loads
        } else {
            val[it] = make_float2(1.f / (1.f + expf(-ab[v])),
                                  1.f / (1.f + expf(-at[v])));
        }
    }

    const int  ray1 = tid + 1024;
    const bool has1 = (ray1 < NRAYS);   // tid < 576, wave-uniform (576 = 9*64)
    float S0 = 0.f, T0 = 1.f, S1 = 0.f, T1 = 1.f;

    for (int p = 0; p < NP; ++p) {
        const unsigned lo = (unsigned)(p * CELLS);

        // --- init slab to (0,0) ---
        uint4* g4 = (uint4*)grid;
        const uint4 z4 = make_uint4(0u, 0u, 0u, 0u);
        for (int c = tid; c < CELLS / 2; c += 1024)
            g4[c] = z4;
        __syncthreads();

        // --- scatter this slab's voxels (register replay, no global ops) ---
        #pragma unroll
        for (int it = 0; it < 32; ++it) {
            const unsigned cell = (cpk[it >> 1] >> ((it & 1) << 4)) & 0xFFFFu;
            const unsigned rel  = cell - lo;       // wraps if below lo
            if (rel < (unsigned)CELLS)
                grid[rel] = val[it];   // dup cells: racy single-inst write = unspecified winner
        }
        __syncthreads();

        // --- march slab: rays tid and tid+1024 ---
        #pragma unroll
        for (int zl = 0; zl < DEPTH; ++zl) {
            const int base = zl * NRAYS;
            const float2 p0 = grid[base + tid];
            S0 = fmaf(T0 * p0.y, p0.x, S0);
            T0 *= (1.f - p0.y);
            if (has1) {
                const float2 p1 = grid[base + ray1];
                S1 = fmaf(T1 * p1.y, p1.x, S1);
                T1 *= (1.f - p1.y);
            }
        }
        __syncthreads();   // protect grid before next slab's init
    }

    out[b * NRAYS + tid] = S0;
    if (has1) out[b * NRAYS + ray1] = S1;
}

extern "C" void kernel_launch(void* const* d_in, const int* in_sizes, int n_in,
                              void* d_out, int out_size, void* d_ws, size_t ws_size,
                              hipStream_t stream)
{
    const float* Rall = (const float*)d_in[0];   // [512,3,3]
    const float* ab   = (const float*)d_in[1];   // [32,32,32,1]
    const float* at   = (const float*)d_in[2];   // [32,32,32,1]
    float*       out  = (float*)d_out;           // [512,40,40,1]
    float2*      pre  = (float2*)d_ws;

    const bool use_pre = ws_size >= (size_t)NVOX * sizeof(float2);

    // DEPTH=10 slab = 128000 B dynamic LDS: needs the >64KB opt-in (gfx950
    // allows up to 160 KiB/WG). Host-side attribute set, safe under capture.
    hipError_t e1 = hipFuncSetAttribute(
        reinterpret_cast<const void*>(&render_kernel<10, true>),
        hipFuncAttributeMaxDynamicSharedMemorySize, 10 * NRAYS * 8);
    hipError_t e2 = hipFuncSetAttribute(
        reinterpret_cast<const void*>(&render_kernel<10, false>),
        hipFuncAttributeMaxDynamicSharedMemorySize, 10 * NRAYS * 8);
    const bool big = (e1 == hipSuccess) && (e2 == hipSuccess);

    if (use_pre)
        prep_kernel<<<(NVOX + 255) / 256, 256, 0, stream>>>(ab, at, pre);

    if (big) {
        if (use_pre)
            render_kernel<10, true ><<<NBATCH, 1024, 10 * NRAYS * 8, stream>>>(Rall, pre, ab, at, out);
        else
            render_kernel<10, false><<<NBATCH, 1024, 10 * NRAYS * 8, stream>>>(Rall, pre, ab, at, out);
    } else {
        // DEPTH=5 slab = 64000 B dynamic LDS: under the default 64 KB cap
        if (use_pre)
            render_kernel<5, true ><<<NBATCH, 1024, 5 * NRAYS * 8, stream>>>(Rall, pre, ab, at, out);
        else
            render_kernel<5, false><<<NBATCH, 1024, 5 * NRAYS * 8, stream>>>(Rall, pre, ab, at, out);
    }
}

// Round 5
// 156.874 us; speedup vs baseline: 1.0029x; 1.0029x over previous
//
#include <hip/hip_runtime.h>
#include <hip/hip_bf16.h>

// DifferentiableRenderer R5 = R4 + the spill fix.
// R4 (109 us) was scratch-bound: bare __launch_bounds__(1024) let the
// compiler cap VGPR at 64, spilling val[32] (64 VGPR) + cpk[16] to scratch
// -> 167 MB HBM traffic (matched FETCH+WRITE ~182 MB). Fix:
// __launch_bounds__(1024, 4) -> 4 waves/EU min -> VGPR cap 128 (the 125 KB
// LDS already forces 1 block/CU, so nothing is lost). ~105 VGPR needed.
//
// Structure (unchanged from R4): scatter VALUES (float2 sigmoid(a),sigmoid(t))
// into a z-major LDS grid; 4 passes of depth-10 slabs ([10][1600] float2 =
// 125 KB dynamic LDS). Per-thread cache of 32 dest cells (u16-packed) + 32
// float2 values, replayed per pass. Empty cell = (0,0) -> exact no-op
// (sigmoid(-1e9) == 0 in fp32). pre[] reads are coalesced (v = tid+it*1024).
//
// Numerics unchanged (absmax 0.0 in R2/R3/R4): transform
// c = fmaf(z,R2c, fmaf(y,R1c, x*R0c)) + 20, clip [0,39], trunc;
// march S = fmaf(T*t, a, S), T *= (1-t); sigmoids = 1/(1+expf(-x)).

#define NBATCH 512
#define G      40
#define NRAYS  (G*G)       // 1600
#define NVOX   32768

// ---------- prep: per-voxel sigmoid table ----------
__global__ __launch_bounds__(256)
void prep_kernel(const float* __restrict__ ab, const float* __restrict__ at,
                 float2* __restrict__ pre)
{
    const int i = blockIdx.x * 256 + threadIdx.x;
    if (i < NVOX)
        pre[i] = make_float2(1.f / (1.f + expf(-ab[i])),
                             1.f / (1.f + expf(-at[i])));
}

// ---------- render: value grid in LDS, G/DEPTH z-slab passes ----------
template<int DEPTH, bool USE_PRE>
__global__ __launch_bounds__(1024, 4)   // 4 waves/EU min -> VGPR cap 128, no spill
void render_kernel(const float* __restrict__ Rall,
                   const float2* __restrict__ pre,
                   const float* __restrict__ ab,
                   const float* __restrict__ at,
                   float* __restrict__ out)
{
    constexpr int NP    = G / DEPTH;       // passes
    constexpr int CELLS = DEPTH * NRAYS;   // cells per slab
    extern __shared__ float2 grid[];       // [DEPTH][NRAYS], z-major

    const int b   = blockIdx.x;
    const int tid = threadIdx.x;

    const float* R = Rall + b * 9;
    const float r00 = R[0], r01 = R[1], r02 = R[2];
    const float r10 = R[3], r11 = R[4], r12 = R[5];
    const float r20 = R[6], r21 = R[7], r22 = R[8];

    // v = tid + it*1024  =>  i = it, j = (tid>>5)&31, k = tid&31
    const float y = (float)((tid >> 5) & 31) - 16.f;
    const float z = (float)(tid & 31) - 16.f;

    // --- cache: 32 destination cells (u16-packed, 16 VGPR) + 32 float2 (64 VGPR) ---
    unsigned cpk[16];
    float2   val[32];
    #pragma unroll
    for (int it = 0; it < 32; ++it) {
        const float x = (float)it - 16.f;
        const float c0 = fmaf(z, r20, fmaf(y, r10, x * r00)) + 20.f;
        const float c1 = fmaf(z, r21, fmaf(y, r11, x * r01)) + 20.f;
        const float c2 = fmaf(z, r22, fmaf(y, r12, x * r02)) + 20.f;
        const int i0 = (int)fminf(fmaxf(c0, 0.f), 39.f);
        const int i1 = (int)fminf(fmaxf(c1, 0.f), 39.f);
        const int i2 = (int)fminf(fmaxf(c2, 0.f), 39.f);
        const unsigned cell = (unsigned)(i2 * NRAYS + i0 * G + i1); // < 64000, fits u16
        if (it & 1) cpk[it >> 1] |= cell << 16;
        else        cpk[it >> 1]  = cell;
        const int v = tid + (it << 10);
        if (USE_PRE) {
            val[it] = pre[v];                       // coalesced 8B loads
        } else {
            val[it] = make_float2(1.f / (1.f + expf(-ab[v])),
                                  1.f / (1.f + expf(-at[v])));
        }
    }

    const int  ray1 = tid + 1024;
    const bool has1 = (ray1 < NRAYS);   // tid < 576, wave-uniform (576 = 9*64)
    float S0 = 0.f, T0 = 1.f, S1 = 0.f, T1 = 1.f;

    for (int p = 0; p < NP; ++p) {
        const unsigned lo = (unsigned)(p * CELLS);

        // --- init slab to (0,0) ---
        uint4* g4 = (uint4*)grid;
        const uint4 z4 = make_uint4(0u, 0u, 0u, 0u);
        for (int c = tid; c < CELLS / 2; c += 1024)
            g4[c] = z4;
        __syncthreads();

        // --- scatter this slab's voxels (register replay, no global ops) ---
        #pragma unroll
        for (int it = 0; it < 32; ++it) {
            const unsigned cell = (cpk[it >> 1] >> ((it & 1) << 4)) & 0xFFFFu;
            const unsigned rel  = cell - lo;       // wraps if below lo
            if (rel < (unsigned)CELLS)
                grid[rel] = val[it];   // dup cells: racy 8B write = unspecified winner
        }
        __syncthreads();

        // --- march slab: rays tid and tid+1024 ---
        #pragma unroll
        for (int zl = 0; zl < DEPTH; ++zl) {
            const int base = zl * NRAYS;
            const float2 p0 = grid[base + tid];
            S0 = fmaf(T0 * p0.y, p0.x, S0);
            T0 *= (1.f - p0.y);
            if (has1) {
                const float2 p1 = grid[base + ray1];
                S1 = fmaf(T1 * p1.y, p1.x, S1);
                T1 *= (1.f - p1.y);
            }
        }
        __syncthreads();   // protect grid before next slab's init
    }

    out[b * NRAYS + tid] = S0;
    if (has1) out[b * NRAYS + ray1] = S1;
}

extern "C" void kernel_launch(void* const* d_in, const int* in_sizes, int n_in,
                              void* d_out, int out_size, void* d_ws, size_t ws_size,
                              hipStream_t stream)
{
    const float* Rall = (const float*)d_in[0];   // [512,3,3]
    const float* ab   = (const float*)d_in[1];   // [32,32,32,1]
    const float* at   = (const float*)d_in[2];   // [32,32,32,1]
    float*       out  = (float*)d_out;           // [512,40,40,1]
    float2*      pre  = (float2*)d_ws;

    const bool use_pre = ws_size >= (size_t)NVOX * sizeof(float2);

    // DEPTH=10 slab = 128000 B dynamic LDS: needs the >64KB opt-in (gfx950
    // allows up to 160 KiB/WG). Host-side attribute set, safe under capture.
    hipError_t e1 = hipFuncSetAttribute(
        reinterpret_cast<const void*>(&render_kernel<10, true>),
        hipFuncAttributeMaxDynamicSharedMemorySize, 10 * NRAYS * 8);
    hipError_t e2 = hipFuncSetAttribute(
        reinterpret_cast<const void*>(&render_kernel<10, false>),
        hipFuncAttributeMaxDynamicSharedMemorySize, 10 * NRAYS * 8);
    const bool big = (e1 == hipSuccess) && (e2 == hipSuccess);

    if (use_pre)
        prep_kernel<<<(NVOX + 255) / 256, 256, 0, stream>>>(ab, at, pre);

    if (big) {
        if (use_pre)
            render_kernel<10, true ><<<NBATCH, 1024, 10 * NRAYS * 8, stream>>>(Rall, pre, ab, at, out);
        else
            render_kernel<10, false><<<NBATCH, 1024, 10 * NRAYS * 8, stream>>>(Rall, pre, ab, at, out);
    } else {
        // DEPTH=5 slab = 64000 B dynamic LDS: under the default 64 KB cap
        if (use_pre)
            render_kernel<5, true ><<<NBATCH, 1024, 5 * NRAYS * 8, stream>>>(Rall, pre, ab, at, out);
        else
            render_kernel<5, false><<<NBATCH, 1024, 5 * NRAYS * 8, stream>>>(Rall, pre, ab, at, out);
    }
}

// Round 11
// 113.860 us; speedup vs baseline: 1.3818x; 1.3778x over previous
//
#include <hip/hip_runtime.h>
#include <hip/hip_bf16.h>

// DifferentiableRenderer R11 = R8/R9/R10 resubmitted (infra timeouts; never measured).
// R4/R5 (~100 us) were scratch-bound: val[32]+cpk[16] (80 VGPR) vs the
// compiler's 64-VGPR cap (dynamic LDS hides the 1-block/CU occupancy, so
// its 8-waves/EU heuristic spills). This version removes the dependence on
// any attribute taking effect: NO val[] cache -- pre[v] is loaded lazily
// inside the scatter, predicated on the slab-range test. Each voxel belongs
// to exactly one slab, so total loads are unchanged (32/thread/kernel);
// they are L2-resident (256 KB table) and hidden by 16 waves/block.
// Register need: cpk[16] + R(9) + misc ~= 50 VGPR < 64 -> no spill even if
// the waves_per_eu(4,4) pin is ignored.
//
// Structure: scatter VALUES (float2 sigmoid(a),sigmoid(t)) into a z-major
// LDS grid; 4 passes of depth-10 slabs ([10][1600] float2 = 125 KB dynamic
// LDS; DEPTH=5/64 KB fallback). Dest cells cached u16-packed in cpk[16].
// Empty cell = (0,0) -> exact no-op (sigmoid(-1e9) == 0 in fp32).
//
// Numerics unchanged (absmax 0.0 in R2-R5): transform
// c = fmaf(z,R2c, fmaf(y,R1c, x*R0c)) + 20, clip [0,39], trunc;
// march S = fmaf(T*t, a, S), T *= (1-t); sigmoids = 1/(1+expf(-x)).

#define NBATCH 512
#define G      40
#define NRAYS  (G*G)       // 1600
#define NVOX   32768

// ---------- prep: per-voxel sigmoid table ----------
__global__ __launch_bounds__(256)
void prep_kernel(const float* __restrict__ ab, const float* __restrict__ at,
                 float2* __restrict__ pre)
{
    const int i = blockIdx.x * 256 + threadIdx.x;
    if (i < NVOX)
        pre[i] = make_float2(1.f / (1.f + expf(-ab[i])),
                             1.f / (1.f + expf(-at[i])));
}

// ---------- render: value grid in LDS, G/DEPTH z-slab passes ----------
template<int DEPTH, bool USE_PRE>
__global__ __launch_bounds__(1024)
__attribute__((amdgpu_waves_per_eu(4, 4)))   // pin (bonus); kernel no longer NEEDS it
void render_kernel(const float* __restrict__ Rall,
                   const float2* __restrict__ pre,
                   const float* __restrict__ ab,
                   const float* __restrict__ at,
                   float* __restrict__ out)
{
    constexpr int NP    = G / DEPTH;       // passes
    constexpr int CELLS = DEPTH * NRAYS;   // cells per slab
    extern __shared__ float2 grid[];       // [DEPTH][NRAYS], z-major

    const int b   = blockIdx.x;
    const int tid = threadIdx.x;

    const float* R = Rall + b * 9;
    const float r00 = R[0], r01 = R[1], r02 = R[2];
    const float r10 = R[3], r11 = R[4], r12 = R[5];
    const float r20 = R[6], r21 = R[7], r22 = R[8];

    // v = tid + it*1024  =>  i = it, j = (tid>>5)&31, k = tid&31
    const float y = (float)((tid >> 5) & 31) - 16.f;
    const float z = (float)(tid & 31) - 16.f;

    // --- cache destination cells only (u16-packed, 16 VGPR) ---
    unsigned cpk[16];
    #pragma unroll
    for (int it = 0; it < 32; ++it) {
        const float x = (float)it - 16.f;
        const float c0 = fmaf(z, r20, fmaf(y, r10, x * r00)) + 20.f;
        const float c1 = fmaf(z, r21, fmaf(y, r11, x * r01)) + 20.f;
        const float c2 = fmaf(z, r22, fmaf(y, r12, x * r02)) + 20.f;
        const int i0 = (int)fminf(fmaxf(c0, 0.f), 39.f);
        const int i1 = (int)fminf(fmaxf(c1, 0.f), 39.f);
        const int i2 = (int)fminf(fmaxf(c2, 0.f), 39.f);
        const unsigned cell = (unsigned)(i2 * NRAYS + i0 * G + i1); // < 64000, fits u16
        if (it & 1) cpk[it >> 1] |= cell << 16;
        else        cpk[it >> 1]  = cell;
    }

    const int  ray1 = tid + 1024;
    const bool has1 = (ray1 < NRAYS);   // tid < 576, wave-uniform (576 = 9*64)
    float S0 = 0.f, T0 = 1.f, S1 = 0.f, T1 = 1.f;

    for (int p = 0; p < NP; ++p) {
        const unsigned lo = (unsigned)(p * CELLS);

        // --- init slab to (0,0) ---
        uint4* g4 = (uint4*)grid;
        const uint4 z4 = make_uint4(0u, 0u, 0u, 0u);
        for (int c = tid; c < CELLS / 2; c += 1024)
            g4[c] = z4;
        __syncthreads();

        // --- scatter: lazy predicated value load (each voxel hits ONE pass) ---
        #pragma unroll
        for (int it = 0; it < 32; ++it) {
            const unsigned cell = (cpk[it >> 1] >> ((it & 1) << 4)) & 0xFFFFu;
            const unsigned rel  = cell - lo;       // wraps if below lo
            if (rel < (unsigned)CELLS) {
                const int v = tid + (it << 10);
                if (USE_PRE) {
                    grid[rel] = pre[v];            // L2-resident 8B load
                } else {
                    grid[rel] = make_float2(1.f / (1.f + expf(-ab[v])),
                                            1.f / (1.f + expf(-at[v])));
                }
                // dup cells: racy 8B write = unspecified winner (JAX set)
            }
        }
        __syncthreads();

        // --- march slab: rays tid and tid+1024 ---
        #pragma unroll
        for (int zl = 0; zl < DEPTH; ++zl) {
            const int base = zl * NRAYS;
            const float2 p0 = grid[base + tid];
            S0 = fmaf(T0 * p0.y, p0.x, S0);
            T0 *= (1.f - p0.y);
            if (has1) {
                const float2 p1 = grid[base + ray1];
                S1 = fmaf(T1 * p1.y, p1.x, S1);
                T1 *= (1.f - p1.y);
            }
        }
        __syncthreads();   // protect grid before next slab's init
    }

    out[b * NRAYS + tid] = S0;
    if (has1) out[b * NRAYS + ray1] = S1;
}

extern "C" void kernel_launch(void* const* d_in, const int* in_sizes, int n_in,
                              void* d_out, int out_size, void* d_ws, size_t ws_size,
                              hipStream_t stream)
{
    const float* Rall = (const float*)d_in[0];   // [512,3,3]
    const float* ab   = (const float*)d_in[1];   // [32,32,32,1]
    const float* at   = (const float*)d_in[2];   // [32,32,32,1]
    float*       out  = (float*)d_out;           // [512,40,40,1]
    float2*      pre  = (float2*)d_ws;

    const bool use_pre = ws_size >= (size_t)NVOX * sizeof(float2);

    // DEPTH=10 slab = 128000 B dynamic LDS: needs the >64KB opt-in (gfx950
    // allows up to 160 KiB/WG). Host-side attribute set, safe under capture.
    hipError_t e1 = hipFuncSetAttribute(
        reinterpret_cast<const void*>(&render_kernel<10, true>),
        hipFuncAttributeMaxDynamicSharedMemorySize, 10 * NRAYS * 8);
    hipError_t e2 = hipFuncSetAttribute(
        reinterpret_cast<const void*>(&render_kernel<10, false>),
        hipFuncAttributeMaxDynamicSharedMemorySize, 10 * NRAYS * 8);
    const bool big = (e1 == hipSuccess) && (e2 == hipSuccess);

    if (use_pre)
        prep_kernel<<<(NVOX + 255) / 256, 256, 0, stream>>>(ab, at, pre);

    if (big) {
        if (use_pre)
            render_kernel<10, true ><<<NBATCH, 1024, 10 * NRAYS * 8, stream>>>(Rall, pre, ab, at, out);
        else
            render_kernel<10, false><<<NBATCH, 1024, 10 * NRAYS * 8, stream>>>(Rall, pre, ab, at, out);
    } else {
        // DEPTH=5 slab = 64000 B dynamic LDS: under the default 64 KB cap
        if (use_pre)
            render_kernel<5, true ><<<NBATCH, 1024, 5 * NRAYS * 8, stream>>>(Rall, pre, ab, at, out);
        else
            render_kernel<5, false><<<NBATCH, 1024, 5 * NRAYS * 8, stream>>>(Rall, pre, ab, at, out);
    }
}